// Round 5
// baseline (857.089 us; speedup 1.0000x reference)
//
#include <hip/hip_runtime.h>
#include <hip/hip_cooperative_groups.h>
#include <math.h>

namespace cg = cooperative_groups;

#define FP 96    // F*P floats per node
#define SLOT 64  // max in-degree bucket capacity (dataset max ~45, Poisson(16))
#define NPB 16   // nodes per gather tile
#define BLK 256
#define GRID 1024  // 4 blocks/CU x 256 CU — co-resident under __launch_bounds__(256,4)

__device__ __forceinline__ unsigned f2bf_bits(float f) {
    unsigned u = __float_as_uint(f);
    return (u + 0x7fffu + ((u >> 16) & 1u)) >> 16;   // round-to-nearest-even
}
__device__ __forceinline__ float bf_lo(unsigned u) { return __uint_as_float(u << 16); }
__device__ __forceinline__ float bf_hi(unsigned u) { return __uint_as_float(u & 0xffff0000u); }

// ---- shared smem layout for the gather/gates tile routine
struct TileSmem {
    float sy[NPB][FP + 4];   // aggregated rows (+4 pad)
    float shr[NPB][32];      // relu(Hacc)
    float scst[984];         // Mz(256) Mh(256) cz(32) ch(32) probs(12,@576) out_w(384,@588) out_b(12,@972)
    int   sbuck[NPB][68];    // bucket lists (row stride 68: 16B-aligned, bank-shifted)
    int   sdeg[NPB];         // raw in-degree
};

// ---- weight fold: one 256-thread block fills cst[0..983]
__device__ __forceinline__ void fold_weights(int t,
        const float* __restrict__ Wz, const float* __restrict__ bz,
        const float* __restrict__ Wh, const float* __restrict__ bh,
        const float* __restrict__ lz_w, const float* __restrict__ lz_b,
        const float* __restrict__ lh_w, const float* __restrict__ lh_b,
        const float* __restrict__ att, const float* __restrict__ out_w,
        const float* __restrict__ out_b, float* __restrict__ cst) {
    int f = t >> 5, o = t & 31;
    float sz = 0.f, sh = 0.f;
    for (int j = 0; j < 32; ++j) {
        sz += Wz[f * 32 + j] * lz_w[o * 64 + j];
        sh += Wh[f * 32 + j] * lh_w[o * 64 + j];
    }
    cst[t]       = sz;   // Mz
    cst[256 + t] = sh;   // Mh
    if (t < 32) {
        float a = lz_b[t], c = lh_b[t];
        for (int j = 0; j < 32; ++j) {
            a += bz[j] * lz_w[t * 64 + j];
            c += bh[j] * lh_w[t * 64 + j];
        }
        cst[512 + t] = a;  // cz
        cst[544 + t] = c;  // ch
    }
    if (t < 12) {
        float m = -1e30f;
        for (int p = 0; p < 12; ++p) m = fmaxf(m, att[p]);
        float s = 0.f;
        for (int p = 0; p < 12; ++p) s += expf(att[p] - m);
        cst[576 + t] = expf(att[t] - m) / s;  // probs
    }
    for (int i = t; i < 384; i += BLK) cst[588 + i] = out_w[i];  // out_w [12x32]
    if (t < 12) cst[972 + t] = out_b[t];
}

// ---- prescaled bf16 convert of one 8-float chunk: xb[i] = bf16(dinv[n] * x[i*8..])
__device__ __forceinline__ void convert_chunk(int i, const float* __restrict__ x,
                                              const int* __restrict__ cnt,
                                              unsigned* __restrict__ xb) {
    int n = i / 12;
    float w = rsqrtf((float)(cnt[n] + 1));
    const float4* x4 = (const float4*)x;
    float4 a = x4[i * 2], c = x4[i * 2 + 1];
    uint4 r;
    r.x = f2bf_bits(w * a.x) | (f2bf_bits(w * a.y) << 16);
    r.y = f2bf_bits(w * a.z) | (f2bf_bits(w * a.w) << 16);
    r.z = f2bf_bits(w * c.x) | (f2bf_bits(w * c.y) << 16);
    r.w = f2bf_bits(w * c.z) | (f2bf_bits(w * c.w) << 16);
    ((uint4*)xb)[i] = r;
}

// ---- one 16-node tile: LDS-staged buckets -> gather -> gates -> output
// requires sm.scst already populated and a __syncthreads since its last write.
__device__ __forceinline__ void gather_tile(TileSmem& sm, int tile, int t,
                                            const uint4* __restrict__ xrow,
                                            const int* __restrict__ cnt,
                                            const int* __restrict__ bucket,
                                            float* __restrict__ out, int N) {
    int n0 = tile * NPB;
    if (t < NPB) sm.sdeg[t] = (n0 + t < N) ? cnt[n0 + t] : 0;
    {   // stage bucket lists: 16 nodes x 16 quads, int4 each, coalesced
        int nd = t >> 4, q = t & 15, n = n0 + nd;
        if (n < N) *(int4*)&sm.sbuck[nd][q * 4] =
            ((const int4*)(bucket + (size_t)n * SLOT))[q];
    }
    __syncthreads();
    if (t < NPB * 12) {
        int nl = t / 12, k = t - nl * 12, n = n0 + nl;
        if (n < N) {
            int c = sm.sdeg[nl];
            int deg = min(c, SLOT);
            uint4 v = xrow[n * 12 + k];   // self term (pre-scaled)
            float acc[8] = {bf_lo(v.x), bf_hi(v.x), bf_lo(v.y), bf_hi(v.y),
                            bf_lo(v.z), bf_hi(v.z), bf_lo(v.w), bf_hi(v.w)};
            int j = 0;
            for (; j + 4 <= deg; j += 4) {
                int s0 = sm.sbuck[nl][j],     s1 = sm.sbuck[nl][j + 1];
                int s2 = sm.sbuck[nl][j + 2], s3 = sm.sbuck[nl][j + 3];
                uint4 v0 = xrow[s0 * 12 + k], v1 = xrow[s1 * 12 + k];
                uint4 v2 = xrow[s2 * 12 + k], v3 = xrow[s3 * 12 + k];
                acc[0] += bf_lo(v0.x) + bf_lo(v1.x) + bf_lo(v2.x) + bf_lo(v3.x);
                acc[1] += bf_hi(v0.x) + bf_hi(v1.x) + bf_hi(v2.x) + bf_hi(v3.x);
                acc[2] += bf_lo(v0.y) + bf_lo(v1.y) + bf_lo(v2.y) + bf_lo(v3.y);
                acc[3] += bf_hi(v0.y) + bf_hi(v1.y) + bf_hi(v2.y) + bf_hi(v3.y);
                acc[4] += bf_lo(v0.z) + bf_lo(v1.z) + bf_lo(v2.z) + bf_lo(v3.z);
                acc[5] += bf_hi(v0.z) + bf_hi(v1.z) + bf_hi(v2.z) + bf_hi(v3.z);
                acc[6] += bf_lo(v0.w) + bf_lo(v1.w) + bf_lo(v2.w) + bf_lo(v3.w);
                acc[7] += bf_hi(v0.w) + bf_hi(v1.w) + bf_hi(v2.w) + bf_hi(v3.w);
            }
            for (; j < deg; ++j) {
                int s = sm.sbuck[nl][j];
                uint4 w = xrow[s * 12 + k];
                acc[0] += bf_lo(w.x); acc[1] += bf_hi(w.x);
                acc[2] += bf_lo(w.y); acc[3] += bf_hi(w.y);
                acc[4] += bf_lo(w.z); acc[5] += bf_hi(w.z);
                acc[6] += bf_lo(w.w); acc[7] += bf_hi(w.w);
            }
            float di = rsqrtf((float)(c + 1));
#pragma unroll
            for (int i = 0; i < 8; ++i) sm.sy[nl][k * 8 + i] = di * acc[i];
        }
    }
    __syncthreads();
    int o = t & 31;
#pragma unroll
    for (int it = 0; it < 2; ++it) {
        int local = (t >> 5) + it * 8, n = n0 + local;
        if (n < N) {
            float cz = sm.scst[512 + o], ch = sm.scst[544 + o];
            float hacc = 0.f;
#pragma unroll
            for (int p = 0; p < 12; ++p) {
                float az = cz, ah = ch;
#pragma unroll
                for (int f = 0; f < 8; ++f) {
                    float xf = sm.sy[local][f * 12 + p];
                    az += xf * sm.scst[f * 32 + o];
                    ah += xf * sm.scst[256 + f * 32 + o];
                }
                float Z  = 1.f / (1.f + expf(-az));
                float Ht = tanhf(ah);
                hacc += sm.scst[576 + p] * (1.f - Z) * Ht;
            }
            sm.shr[local][o] = fmaxf(hacc, 0.f);
        }
    }
    __syncthreads();
#pragma unroll
    for (int it = 0; it < 2; ++it) {
        int local = (t >> 5) + it * 8, n = n0 + local;
        if (n < N && o < 12) {
            float s = sm.scst[972 + o];
#pragma unroll
            for (int j2 = 0; j2 < 32; ++j2)
                s += sm.shr[local][j2] * sm.scst[588 + o * 32 + j2];
            out[(size_t)n * 12 + o] = s;
        }
    }
    __syncthreads();  // protect smem before next tile restages
}

// =======================  single cooperative kernel  =======================
__global__ void __launch_bounds__(BLK, 4)
k_fused(const float* __restrict__ x, const int* __restrict__ ei,
        const float* __restrict__ Wz, const float* __restrict__ bz,
        const float* __restrict__ Wh, const float* __restrict__ bh,
        const float* __restrict__ lz_w, const float* __restrict__ lz_b,
        const float* __restrict__ lh_w, const float* __restrict__ lh_b,
        const float* __restrict__ att, const float* __restrict__ out_w,
        const float* __restrict__ out_b, float* __restrict__ out,
        int* __restrict__ cnt, int* __restrict__ bucket,
        unsigned* __restrict__ xb, float* __restrict__ cst, int N, int E) {
    cg::grid_group grid = cg::this_grid();
    const int t = threadIdx.x, bid = blockIdx.x;
    const int gtid = bid * BLK + t, gthreads = gridDim.x * BLK;

    // P1: zero cnt
    for (int i = gtid; i < N; i += gthreads) cnt[i] = 0;
    __threadfence(); grid.sync(); __threadfence();

    // P2: bucket fill
    for (int e = gtid; e < E; e += gthreads) {
        int src = ei[e], dst = ei[E + e];
        int pos = atomicAdd(cnt + dst, 1);
        if (pos < SLOT) bucket[(size_t)dst * SLOT + pos] = src;
    }
    __threadfence(); grid.sync(); __threadfence();

    // P3: weight fold (block 0) + prescaled bf16 convert (blocks 1..)
    if (bid == 0) {
        fold_weights(t, Wz, bz, Wh, bh, lz_w, lz_b, lh_w, lh_b, att, out_w, out_b, cst);
    } else {
        for (int i = (bid - 1) * BLK + t; i < N * 12; i += (gridDim.x - 1) * BLK)
            convert_chunk(i, x, cnt, xb);
    }
    __threadfence(); grid.sync(); __threadfence();

    // P4: gather + gates + attention + output, tiles grid-strided
    __shared__ TileSmem sm;
    for (int i = t; i < 984; i += BLK) sm.scst[i] = cst[i];
    // first __syncthreads inside gather_tile covers scst visibility
    const uint4* xrow = (const uint4*)xb;
    int ntiles = (N + NPB - 1) / NPB;
    for (int tile = bid; tile < ntiles; tile += gridDim.x)
        gather_tile(sm, tile, t, xrow, cnt, bucket, out, N);
}

// =======================  fallback multi-launch path  =======================
__global__ void k_histfill(const int* __restrict__ ei, int E,
                           int* __restrict__ cnt, int* __restrict__ bucket) {
    int e = blockIdx.x * blockDim.x + threadIdx.x;
    if (e >= E) return;
    int src = ei[e], dst = ei[E + e];
    int pos = atomicAdd(cnt + dst, 1);
    if (pos < SLOT) bucket[(size_t)dst * SLOT + pos] = src;
}

__global__ void k_prep(const float* __restrict__ Wz, const float* __restrict__ bz,
                       const float* __restrict__ Wh, const float* __restrict__ bh,
                       const float* __restrict__ lz_w, const float* __restrict__ lz_b,
                       const float* __restrict__ lh_w, const float* __restrict__ lh_b,
                       const float* __restrict__ att, const float* __restrict__ out_w,
                       const float* __restrict__ out_b, const float* __restrict__ x,
                       const int* __restrict__ cnt, float* __restrict__ cst,
                       unsigned* __restrict__ xb, int N) {
    int b = blockIdx.x, t = threadIdx.x;
    if (b == 0) {
        fold_weights(t, Wz, bz, Wh, bh, lz_w, lz_b, lh_w, lh_b, att, out_w, out_b, cst);
    } else {
        int i = (b - 1) * BLK + t;
        if (i < N * 12) convert_chunk(i, x, cnt, xb);
    }
}

__global__ void k_gather_gates(const unsigned* __restrict__ xb, const int* __restrict__ cnt,
                               const int* __restrict__ bucket, const float* __restrict__ cst,
                               float* __restrict__ out, int N) {
    __shared__ TileSmem sm;
    int t = threadIdx.x;
    for (int i = t; i < 984; i += BLK) sm.scst[i] = cst[i];
    gather_tile(sm, blockIdx.x, t, (const uint4*)xb, cnt, bucket, out, N);
}

extern "C" void kernel_launch(void* const* d_in, const int* in_sizes, int n_in,
                              void* d_out, int out_size, void* d_ws, size_t ws_size,
                              hipStream_t stream) {
    const float* x    = (const float*)d_in[0];
    const int*   ei   = (const int*)d_in[1];
    const float* Wz   = (const float*)d_in[2];
    const float* bz   = (const float*)d_in[3];
    // d_in[4], d_in[5]  (Wr, br)  — dead: H = 0 makes the reset gate a no-op
    const float* Wh   = (const float*)d_in[6];
    const float* bh   = (const float*)d_in[7];
    const float* lz_w = (const float*)d_in[8];
    const float* lz_b = (const float*)d_in[9];
    // d_in[10], d_in[11] (lr_w, lr_b) — dead
    const float* lh_w = (const float*)d_in[12];
    const float* lh_b = (const float*)d_in[13];
    const float* att  = (const float*)d_in[14];
    const float* ow   = (const float*)d_in[15];
    const float* ob   = (const float*)d_in[16];
    float* out = (float*)d_out;

    int N = in_sizes[0] / FP;   // 20000
    int E = in_sizes[1] / 2;    // 320000

    // workspace: cnt[N] | bucket[N*SLOT] | xb[N*48 uints] | cst[984]
    int*      cnt    = (int*)d_ws;
    int*      bucket = cnt + N;
    unsigned* xb     = (unsigned*)(bucket + (size_t)N * SLOT);
    float*    cst    = (float*)(xb + (size_t)N * 48);

    void* kp[] = {(void*)&x, (void*)&ei, (void*)&Wz, (void*)&bz, (void*)&Wh, (void*)&bh,
                  (void*)&lz_w, (void*)&lz_b, (void*)&lh_w, (void*)&lh_b, (void*)&att,
                  (void*)&ow, (void*)&ob, (void*)&out, (void*)&cnt, (void*)&bucket,
                  (void*)&xb, (void*)&cst, (void*)&N, (void*)&E};
    hipError_t err = hipLaunchCooperativeKernel((const void*)k_fused, dim3(GRID), dim3(BLK),
                                                kp, 0, stream);
    if (err != hipSuccess) {
        // fallback: classic multi-launch pipeline (identical math)
        hipMemsetAsync(cnt, 0, (size_t)N * sizeof(int), stream);
        k_histfill<<<(E + BLK - 1) / BLK, BLK, 0, stream>>>(ei, E, cnt, bucket);
        int CB = (N * 12 + BLK - 1) / BLK;
        k_prep<<<1 + CB, BLK, 0, stream>>>(Wz, bz, Wh, bh, lz_w, lz_b, lh_w, lh_b,
                                           att, ow, ob, x, cnt, cst, xb, N);
        k_gather_gates<<<(N + NPB - 1) / NPB, BLK, 0, stream>>>(xb, cnt, bucket, cst, out, N);
    }
}

// Round 6
// 145.064 us; speedup vs baseline: 5.9083x; 5.9083x over previous
//
#include <hip/hip_runtime.h>
#include <math.h>

#define FP 96     // F*P floats per node
#define SLOT 64   // max in-degree bucket capacity (dataset max ~45, Poisson(16))
#define NPB 8     // nodes per gather tile
#define GBLK 128  // gather block size (2 waves)
#define PBLK 256  // prep block size

__device__ __forceinline__ unsigned f2bf_bits(float f) {
    unsigned u = __float_as_uint(f);
    return (u + 0x7fffu + ((u >> 16) & 1u)) >> 16;   // round-to-nearest-even
}
__device__ __forceinline__ float bf_lo(unsigned u) { return __uint_as_float(u << 16); }
__device__ __forceinline__ float bf_hi(unsigned u) { return __uint_as_float(u & 0xffff0000u); }

// ---------- K1 (multi-role):
//   block 0   : fold weights -> cst[984]
//               Mz(0) Mh(256) cz(512) ch(544) probs(576) out_w^T(588, [j*12+o]) out_b(972)
//   blocks 1..: xb[i] = bf16(x[i*8..])  (UNSCALED) + one lane per node zeroes cnt[n]
__global__ void k_pre(const float* __restrict__ Wz, const float* __restrict__ bz,
                      const float* __restrict__ Wh, const float* __restrict__ bh,
                      const float* __restrict__ lz_w, const float* __restrict__ lz_b,
                      const float* __restrict__ lh_w, const float* __restrict__ lh_b,
                      const float* __restrict__ att, const float* __restrict__ out_w,
                      const float* __restrict__ out_b, const float* __restrict__ x,
                      float* __restrict__ cst, int* __restrict__ cnt,
                      unsigned* __restrict__ xb, int N) {
    int b = blockIdx.x, t = threadIdx.x;
    if (b == 0) {
        int f = t >> 5, o = t & 31;
        float sz = 0.f, sh = 0.f;
        for (int j = 0; j < 32; ++j) {
            sz += Wz[f * 32 + j] * lz_w[o * 64 + j];
            sh += Wh[f * 32 + j] * lh_w[o * 64 + j];
        }
        cst[t]       = sz;   // Mz
        cst[256 + t] = sh;   // Mh
        if (t < 32) {
            float a = lz_b[t], c = lh_b[t];
            for (int j = 0; j < 32; ++j) {
                a += bz[j] * lz_w[t * 64 + j];
                c += bh[j] * lh_w[t * 64 + j];
            }
            cst[512 + t] = a;  // cz
            cst[544 + t] = c;  // ch
        }
        if (t < 12) {
            float m = -1e30f;
            for (int p = 0; p < 12; ++p) m = fmaxf(m, att[p]);
            float s = 0.f;
            for (int p = 0; p < 12; ++p) s += expf(att[p] - m);
            cst[576 + t] = expf(att[t] - m) / s;  // probs
        }
        for (int i = t; i < 384; i += PBLK)       // out_w [12x32] -> transposed [32x12]
            cst[588 + (i & 31) * 12 + (i >> 5)] = out_w[i];
        if (t < 12) cst[972 + t] = out_b[t];
    } else {
        int i = (b - 1) * PBLK + t;   // over N*12 chunks of 8 floats
        if (i < N * 12) {
            int n = i / 12;
            if (i - n * 12 == 0) cnt[n] = 0;   // zero cnt inline (12 chunks/node)
            const float4* x4 = (const float4*)x;
            float4 a = x4[i * 2], c = x4[i * 2 + 1];
            uint4 r;
            r.x = f2bf_bits(a.x) | (f2bf_bits(a.y) << 16);
            r.y = f2bf_bits(a.z) | (f2bf_bits(a.w) << 16);
            r.z = f2bf_bits(c.x) | (f2bf_bits(c.y) << 16);
            r.w = f2bf_bits(c.z) | (f2bf_bits(c.w) << 16);
            ((uint4*)xb)[i] = r;
        }
    }
}

// ---------- K2: bucket fill: pos = cnt[dst]++; bucket[dst*SLOT+pos] = src
__global__ void k_histfill(const int* __restrict__ ei, int E,
                           int* __restrict__ cnt, int* __restrict__ bucket) {
    int e = blockIdx.x * blockDim.x + threadIdx.x;
    if (e >= E) return;
    int src = ei[e], dst = ei[E + e];
    int pos = atomicAdd(cnt + dst, 1);
    if (pos < SLOT) bucket[(size_t)dst * SLOT + pos] = src;
}

// ---------- K3: fused gather + gates + attention + relu + output
// agg[n] = dinv[n] * ( dinv[n]*xu[n] + sum_s dinv[s]*xu[s] ),  dinv = rsqrt(cnt+1)
// Phase A (t<96): 8 nodes x 12 lanes; lane owns one uint4 (8 bf16) chunk; x4 unroll,
//                 per-edge weight from L2-hot cnt[] issued parallel to the row load.
// Phase B: 8 nodes x 32 channels over 2 iterations: gates + softmax-weighted sum + relu
// Phase C: output linear [32 -> 12] with transposed out_w (conflict-free)
__global__ void __launch_bounds__(GBLK)
k_gather_gates(const unsigned* __restrict__ xb, const int* __restrict__ cnt,
               const int* __restrict__ bucket, const float* __restrict__ cst,
               float* __restrict__ out, int N) {
    __shared__ float sy[NPB][FP + 4];
    __shared__ float shr[NPB][32];
    __shared__ float scst[984];
    __shared__ int   sbuck[NPB][68];   // stride 68: 16B-aligned, bank-shifted
    __shared__ int   sdeg[NPB];
    int t = threadIdx.x;
    for (int i = t; i < 984; i += GBLK) scst[i] = cst[i];

    int n0 = blockIdx.x * NPB;
    if (t < NPB) sdeg[t] = (n0 + t < N) ? cnt[n0 + t] : 0;
    {   // stage bucket lists: 8 nodes x 16 quads, int4 each — exactly 128 threads
        int nd = t >> 4, q = t & 15, n = n0 + nd;
        if (n < N) *(int4*)&sbuck[nd][q * 4] =
            ((const int4*)(bucket + (size_t)n * SLOT))[q];
    }
    __syncthreads();

    const uint4* xrow = (const uint4*)xb;
    if (t < NPB * 12) {
        int nl = t / 12, k = t - nl * 12, n = n0 + nl;
        if (n < N) {
            int c = sdeg[nl];
            int deg = min(c, SLOT);
            float di = rsqrtf((float)(c + 1));
            uint4 v = xrow[n * 12 + k];   // self term: dinv[n]*xu[n]
            float acc[8] = {di * bf_lo(v.x), di * bf_hi(v.x), di * bf_lo(v.y), di * bf_hi(v.y),
                            di * bf_lo(v.z), di * bf_hi(v.z), di * bf_lo(v.w), di * bf_hi(v.w)};
            int j = 0;
            for (; j + 4 <= deg; j += 4) {
                int s0 = sbuck[nl][j],     s1 = sbuck[nl][j + 1];
                int s2 = sbuck[nl][j + 2], s3 = sbuck[nl][j + 3];
                uint4 v0 = xrow[s0 * 12 + k], v1 = xrow[s1 * 12 + k];
                uint4 v2 = xrow[s2 * 12 + k], v3 = xrow[s3 * 12 + k];
                float w0 = rsqrtf((float)(cnt[s0] + 1));
                float w1 = rsqrtf((float)(cnt[s1] + 1));
                float w2 = rsqrtf((float)(cnt[s2] + 1));
                float w3 = rsqrtf((float)(cnt[s3] + 1));
                acc[0] = fmaf(w0, bf_lo(v0.x), fmaf(w1, bf_lo(v1.x), fmaf(w2, bf_lo(v2.x), fmaf(w3, bf_lo(v3.x), acc[0]))));
                acc[1] = fmaf(w0, bf_hi(v0.x), fmaf(w1, bf_hi(v1.x), fmaf(w2, bf_hi(v2.x), fmaf(w3, bf_hi(v3.x), acc[1]))));
                acc[2] = fmaf(w0, bf_lo(v0.y), fmaf(w1, bf_lo(v1.y), fmaf(w2, bf_lo(v2.y), fmaf(w3, bf_lo(v3.y), acc[2]))));
                acc[3] = fmaf(w0, bf_hi(v0.y), fmaf(w1, bf_hi(v1.y), fmaf(w2, bf_hi(v2.y), fmaf(w3, bf_hi(v3.y), acc[3]))));
                acc[4] = fmaf(w0, bf_lo(v0.z), fmaf(w1, bf_lo(v1.z), fmaf(w2, bf_lo(v2.z), fmaf(w3, bf_lo(v3.z), acc[4]))));
                acc[5] = fmaf(w0, bf_hi(v0.z), fmaf(w1, bf_hi(v1.z), fmaf(w2, bf_hi(v2.z), fmaf(w3, bf_hi(v3.z), acc[5]))));
                acc[6] = fmaf(w0, bf_lo(v0.w), fmaf(w1, bf_lo(v1.w), fmaf(w2, bf_lo(v2.w), fmaf(w3, bf_lo(v3.w), acc[6]))));
                acc[7] = fmaf(w0, bf_hi(v0.w), fmaf(w1, bf_hi(v1.w), fmaf(w2, bf_hi(v2.w), fmaf(w3, bf_hi(v3.w), acc[7]))));
            }
            for (; j < deg; ++j) {
                int s = sbuck[nl][j];
                uint4 w4 = xrow[s * 12 + k];
                float w = rsqrtf((float)(cnt[s] + 1));
                acc[0] = fmaf(w, bf_lo(w4.x), acc[0]); acc[1] = fmaf(w, bf_hi(w4.x), acc[1]);
                acc[2] = fmaf(w, bf_lo(w4.y), acc[2]); acc[3] = fmaf(w, bf_hi(w4.y), acc[3]);
                acc[4] = fmaf(w, bf_lo(w4.z), acc[4]); acc[5] = fmaf(w, bf_hi(w4.z), acc[5]);
                acc[6] = fmaf(w, bf_lo(w4.w), acc[6]); acc[7] = fmaf(w, bf_hi(w4.w), acc[7]);
            }
#pragma unroll
            for (int i = 0; i < 8; ++i) sy[nl][k * 8 + i] = di * acc[i];
        }
    }
    __syncthreads();

    int o = t & 31;
#pragma unroll
    for (int it = 0; it < 2; ++it) {
        int local = (t >> 5) + it * 4, n = n0 + local;
        if (n < N) {
            float cz = scst[512 + o], ch = scst[544 + o];
            float hacc = 0.f;
#pragma unroll
            for (int p = 0; p < 12; ++p) {
                float az = cz, ah = ch;
#pragma unroll
                for (int f = 0; f < 8; ++f) {
                    float xf = sy[local][f * 12 + p];
                    az += xf * scst[f * 32 + o];
                    ah += xf * scst[256 + f * 32 + o];
                }
                float Z  = 1.f / (1.f + expf(-az));
                float Ht = tanhf(ah);
                hacc += scst[576 + p] * (1.f - Z) * Ht;
            }
            shr[local][o] = fmaxf(hacc, 0.f);
        }
    }
    __syncthreads();
#pragma unroll
    for (int it = 0; it < 2; ++it) {
        int local = (t >> 5) + it * 4, n = n0 + local;
        if (n < N && o < 12) {
            float s = scst[972 + o];
#pragma unroll
            for (int j2 = 0; j2 < 32; ++j2)
                s += shr[local][j2] * scst[588 + j2 * 12 + o];  // out_w^T: conflict-free
            out[(size_t)n * 12 + o] = s;
        }
    }
}

extern "C" void kernel_launch(void* const* d_in, const int* in_sizes, int n_in,
                              void* d_out, int out_size, void* d_ws, size_t ws_size,
                              hipStream_t stream) {
    const float* x    = (const float*)d_in[0];
    const int*   ei   = (const int*)d_in[1];
    const float* Wz   = (const float*)d_in[2];
    const float* bz   = (const float*)d_in[3];
    // d_in[4], d_in[5]  (Wr, br)  — dead: H = 0 makes the reset gate a no-op
    const float* Wh   = (const float*)d_in[6];
    const float* bh   = (const float*)d_in[7];
    const float* lz_w = (const float*)d_in[8];
    const float* lz_b = (const float*)d_in[9];
    // d_in[10], d_in[11] (lr_w, lr_b) — dead
    const float* lh_w = (const float*)d_in[12];
    const float* lh_b = (const float*)d_in[13];
    const float* att  = (const float*)d_in[14];
    const float* ow   = (const float*)d_in[15];
    const float* ob   = (const float*)d_in[16];
    float* out = (float*)d_out;

    int N = in_sizes[0] / FP;   // 20000
    int E = in_sizes[1] / 2;    // 320000

    // workspace: cnt[N] | bucket[N*SLOT] | xb[N*48 uints, unscaled bf16 x] | cst[984]
    int*      cnt    = (int*)d_ws;
    int*      bucket = cnt + N;
    unsigned* xb     = (unsigned*)(bucket + (size_t)N * SLOT);
    float*    cst    = (float*)(xb + (size_t)N * 48);

    int CB = (N * 12 + PBLK - 1) / PBLK;   // convert blocks
    k_pre     <<<1 + CB, PBLK, 0, stream>>>(Wz, bz, Wh, bh, lz_w, lz_b, lh_w, lh_b,
                                            att, ow, ob, x, cst, cnt, xb, N);
    k_histfill<<<(E + 255) / 256, 256, 0, stream>>>(ei, E, cnt, bucket);
    k_gather_gates<<<(N + NPB - 1) / NPB, GBLK, 0, stream>>>(xb, cnt, bucket, cst, out, N);
}